// Round 3
// baseline (481.046 us; speedup 1.0000x reference)
//
#include <hip/hip_runtime.h>
#include <stdint.h>

// R11: V fragments load DIRECTLY global->VGPR (prepass layout is already
// MFMA-fragment-linear: 16B/lane contiguous), removing sV from LDS entirely.
// LDS = sK dbuf 32KB + sP 5.1KB = 37.9KB -> 4 blocks/CU (grid cap) restored
// (R8 ran 4 blocks at 29.7KB; R9/R10's larger LDS dropped to 2-3 = the real
// regression). One barrier/iter: K dbuf zero-wait before QK, V waited by
// compiler-counted vmcnt before PV (wave-private), K[kt+1] drained+barrier
// at iter end. K issue uses wrapped index so in-flight count is uniform.
// Numerics/RNG identical to R8/R9/R10.

namespace {

constexpr int Bb  = 32;
constexpr int SQ  = 2048;
constexpr int SKV = 2048;
constexpr int DH  = 128;
constexpr int KT  = 32;
constexpr int NKT = SKV / KT;          // 64
constexpr int TILE_F16 = 12288;        // Khi 4096 | Klo 4096 | Vt 4096 (f16 elems)
constexpr int TILE_U32 = TILE_F16 / 2; // 6144
constexpr size_t WS_NEED = (size_t)Bb * NKT * TILE_F16 * 2;  // 50,331,648 B
constexpr int PSTR = KT + 8;           // 40

typedef _Float16 f16x8 __attribute__((ext_vector_type(8)));
typedef _Float16 f16x4 __attribute__((ext_vector_type(4)));
typedef float    f32x4 __attribute__((ext_vector_type(4)));

__device__ __forceinline__ uint32_t rotl32(uint32_t x, int d) {
  return (x << d) | (x >> (32 - d));
}

// JAX threefry2x32, key=(0,42), counter=(0,i); partitionable bits = x0^x1.
__device__ __forceinline__ uint32_t jax_random_bits(uint32_t i) {
  constexpr uint32_t K0 = 0u;
  constexpr uint32_t K1 = 42u;
  constexpr uint32_t K2 = 0x1BD11BDAu ^ K0 ^ K1;
  uint32_t x0 = K0;
  uint32_t x1 = i + K1;
#define TF4(a,b,c,d) \
  x0 += x1; x1 = rotl32(x1,a); x1 ^= x0; \
  x0 += x1; x1 = rotl32(x1,b); x1 ^= x0; \
  x0 += x1; x1 = rotl32(x1,c); x1 ^= x0; \
  x0 += x1; x1 = rotl32(x1,d); x1 ^= x0;
  TF4(13,15,26,6)   x0 += K1; x1 += K2 + 1u;
  TF4(17,29,16,24)  x0 += K2; x1 += K0 + 2u;
  TF4(13,15,26,6)   x0 += K0; x1 += K1 + 3u;
  TF4(17,29,16,24)  x0 += K1; x1 += K2 + 4u;
  TF4(13,15,26,6)   x0 += K2; x1 += K0 + 5u;
#undef TF4
  return x0 ^ x1;
}

__device__ __forceinline__ bool jax_keep(uint32_t i) {
  const uint32_t fb = (jax_random_bits(i) >> 9) | 0x3f800000u;
  return (__uint_as_float(fb) - 1.0f) < 0.7f;
}

__device__ __forceinline__ _Float16 hi16(float x) { return (_Float16)x; }
__device__ __forceinline__ _Float16 lo16(float x) {
  return (_Float16)(x - (float)((_Float16)x));
}

} // namespace

// ------------- prepass: one block per (b,kt) 32-row tile, coalesced -------------
__global__ __launch_bounds__(256) void prep_tile(const float* __restrict__ Kg,
                                                 const float* __restrict__ Vg,
                                                 _Float16* __restrict__ ws) {
  __shared__ alignas(16) float sT[KT][DH + 4];   // 16.9 KB, reused K then V

  const int tid  = threadIdx.x;
  const int b    = blockIdx.x >> 6;
  const int kt   = blockIdx.x & 63;
  _Float16* tile = ws + (size_t)(b * NKT + kt) * TILE_F16;

  // ---- phase K: coalesced load -> LDS (32 rows x 32 float4)
  {
    const float* kb = Kg + ((size_t)b * SKV + kt * KT) * DH;
#pragma unroll
    for (int rep = 0; rep < 4; ++rep) {
      const int idx = tid + 256 * rep;
      const int row = idx >> 5;
      const int c4  = idx & 31;
      *reinterpret_cast<float4*>(&sT[row][4 * c4]) =
          *reinterpret_cast<const float4*>(kb + (size_t)row * DH + 4 * c4);
    }
  }
  __syncthreads();
  // K hi/lo fragment-linear writes: frag f = ks*2+ct (0..7)
#pragma unroll
  for (int rep = 0; rep < 2; ++rep) {
    const int task = tid + 256 * rep;     // 0..511
    const int lane = task & 63;
    const int f    = task >> 6;           // 0..7
    const int ks   = f >> 1;
    const int ct   = f & 1;
    const int cl   = lane & 15;
    const int g8   = (lane >> 4) * 8;
    const float* src = &sT[ct * 16 + cl][ks * 32 + g8];
    f16x8 h, l;
#pragma unroll
    for (int j = 0; j < 8; ++j) { h[j] = hi16(src[j]); l[j] = lo16(src[j]); }
    *reinterpret_cast<f16x8*>(tile + f * 512 + lane * 8)        = h;
    *reinterpret_cast<f16x8*>(tile + 4096 + f * 512 + lane * 8) = l;
  }
  __syncthreads();

  // ---- phase V
  {
    const float* vb = Vg + ((size_t)b * SKV + kt * KT) * DH;
#pragma unroll
    for (int rep = 0; rep < 4; ++rep) {
      const int idx = tid + 256 * rep;
      const int row = idx >> 5;
      const int c4  = idx & 31;
      *reinterpret_cast<float4*>(&sT[row][4 * c4]) =
          *reinterpret_cast<const float4*>(vb + (size_t)row * DH + 4 * c4);
    }
  }
  __syncthreads();
  // V^T fragment-linear: frag = dt (0..7), elem j = V[g8+j][dt*16+cl]
#pragma unroll
  for (int rep = 0; rep < 2; ++rep) {
    const int task = tid + 256 * rep;
    const int lane = task & 63;
    const int dt   = task >> 6;           // 0..7
    const int cl   = lane & 15;
    const int g8   = (lane >> 4) * 8;
    f16x8 w;
#pragma unroll
    for (int j = 0; j < 8; ++j)
      w[j] = (_Float16)sT[g8 + j][dt * 16 + cl];
    *reinterpret_cast<f16x8*>(tile + 8192 + dt * 512 + lane * 8) = w;
  }
}

// ---------------- main fused kernel: QT=64, KT=32, K-dbuf + V-in-reg ----------------
__global__ __launch_bounds__(256, 4) void fused_attn5(
    const float* __restrict__ Qg, const _Float16* __restrict__ Wk,
    const float* __restrict__ Sg, float* __restrict__ Og)
{
  __shared__ alignas(16) _Float16 sK[2][8192];       // 32 KB: 2x (Khi|Klo)
  __shared__ alignas(16) _Float16 sP[4][16][PSTR];   // 5.1 KB (wave-private)

  const int tid  = threadIdx.x;
  const int wid  = tid >> 6;
  const int lane = tid & 63;
  const int cl   = lane & 15;
  const int g8   = (lane >> 4) * 8;
  const int r0   = (lane >> 4) * 4;

  const int b  = blockIdx.x >> 5;
  const int q0 = (blockIdx.x & 31) * 64;
  const float scale = Sg[b];

  const uint32_t* wbase =
      reinterpret_cast<const uint32_t*>(Wk + (size_t)b * NKT * TILE_F16);

  // ---- prologue: stage K[0] into sK[0] (16 x 1KB chunks, 4 per wave)
#pragma unroll
  for (int c = 0; c < 4; ++c) {
    const int j = wid + 4 * c;          // 0..15
    __builtin_amdgcn_global_load_lds(wbase + j * 256 + lane * 4,
        reinterpret_cast<uint32_t*>(&sK[0][j * 512]), 16, 0, 0);
  }

  // Q A-fragments (hi/lo) in registers: rows q0+wid*16+cl  (overlaps K[0] fetch)
  f16x8 qhi[4], qlo[4];
  {
    const float* qp = Qg + ((size_t)b * SQ + q0 + wid * 16 + cl) * DH + g8;
#pragma unroll
    for (int ks = 0; ks < 4; ++ks) {
      const float4 a0 = *reinterpret_cast<const float4*>(qp + 32 * ks);
      const float4 a1 = *reinterpret_cast<const float4*>(qp + 32 * ks + 4);
      const float xs[8] = {a0.x, a0.y, a0.z, a0.w, a1.x, a1.y, a1.z, a1.w};
#pragma unroll
      for (int j = 0; j < 8; ++j) { qhi[ks][j] = hi16(xs[j]); qlo[ks][j] = lo16(xs[j]); }
    }
  }

  float m_run[4], l_run[4], alpha[4];
  f32x4 oacc[8];
#pragma unroll
  for (int i = 0; i < 4; ++i) { m_run[i] = -INFINITY; l_run[i] = 0.0f; }
#pragma unroll
  for (int dt = 0; dt < 8; ++dt) oacc[dt] = (f32x4){0.f, 0.f, 0.f, 0.f};

  __syncthreads();   // K[0] drained (implicit vmcnt0) + visible

  for (int kt = 0; kt < NKT; ++kt) {
    const int cur = kt & 1;
    const _Float16* wt = Wk + (size_t)(b * NKT + kt) * TILE_F16;

    // ---- issue V[kt] fragments -> registers (8 x dwordx4, oldest in vmcnt
    // queue); consumed at PV after QK+softmax covers the latency.
    f16x8 vfrag[8];
#pragma unroll
    for (int dt = 0; dt < 8; ++dt)
      vfrag[dt] = *reinterpret_cast<const f16x8*>(wt + 8192 + dt * 512 + lane * 8);

    // ---- issue K[kt+1] -> sK[cur^1] (4 x 1KB per wave; wrapped index on the
    // last iter keeps the in-flight count uniform -> counted vmcnt before PV)
    {
      const uint32_t* ksrc = wbase + (size_t)((kt + 1) & (NKT - 1)) * TILE_U32;
#pragma unroll
      for (int c = 0; c < 4; ++c) {
        const int j = wid + 4 * c;
        __builtin_amdgcn_global_load_lds(ksrc + j * 256 + lane * 4,
            reinterpret_cast<uint32_t*>(&sK[cur ^ 1][j * 512]), 16, 0, 0);
      }
    }

    const _Float16* st = sK[cur];

    // ---- S = Q K^T (fp16 hi/lo, fp32 accum): 16x32 per wave — NO wait,
    // K[kt] was drained + barriered at the end of iteration kt-1.
    f32x4 sacc[2];
#pragma unroll
    for (int ct = 0; ct < 2; ++ct) {
      sacc[ct] = (f32x4){0.f, 0.f, 0.f, 0.f};
#pragma unroll
      for (int ks = 0; ks < 4; ++ks) {
        const int f = ks * 2 + ct;
        const f16x8 bhi = *reinterpret_cast<const f16x8*>(&st[f * 512 + lane * 8]);
        const f16x8 blo = *reinterpret_cast<const f16x8*>(&st[4096 + f * 512 + lane * 8]);
        sacc[ct] = __builtin_amdgcn_mfma_f32_16x16x32_f16(qhi[ks], bhi, sacc[ct], 0, 0, 0);
        sacc[ct] = __builtin_amdgcn_mfma_f32_16x16x32_f16(qlo[ks], bhi, sacc[ct], 0, 0, 0);
        sacc[ct] = __builtin_amdgcn_mfma_f32_16x16x32_f16(qhi[ks], blo, sacc[ct], 0, 0, 0);
      }
    }

    // ---- online softmax, per-row fast-path (R6 control flow)
    bool anyalpha = false;
#pragma unroll
    for (int i = 0; i < 4; ++i) {
      float mraw = fmaxf(sacc[0][i], sacc[1][i]);
#pragma unroll
      for (int off = 8; off >= 1; off >>= 1)
        mraw = fmaxf(mraw, __shfl_xor(mraw, off, 64));
      const float mt = mraw * scale;

      if (mt >= m_run[i] - 9.21f) {   // 16-lane-group-uniform per row
        const float mnew = fmaxf(m_run[i], mt);
        alpha[i] = __expf(m_run[i] - mnew);
        m_run[i] = mnew;
        const int qrow = q0 + wid * 16 + r0 + i;
        const uint32_t rowbase =
            ((uint32_t)b * (uint32_t)SQ + (uint32_t)qrow) * (uint32_t)SKV
            + (uint32_t)(kt * KT);
        float ps = 0.0f;
#pragma unroll
        for (int ct = 0; ct < 2; ++ct) {
          const float p = __expf(sacc[ct][i] * scale - mnew);
          ps += p;
          const bool keep = jax_keep(rowbase + (uint32_t)(16 * ct + cl));
          sP[wid][r0 + i][16 * ct + cl] = keep ? (_Float16)(p * (1.0f / 0.7f))
                                               : (_Float16)0.0f;
        }
#pragma unroll
        for (int off = 8; off >= 1; off >>= 1)
          ps += __shfl_xor(ps, off, 64);
        l_run[i] = l_run[i] * alpha[i] + ps;
        anyalpha |= (alpha[i] != 1.0f);
      } else {
        alpha[i] = 1.0f;
#pragma unroll
        for (int ct = 0; ct < 2; ++ct)
          sP[wid][r0 + i][16 * ct + cl] = (_Float16)0.0f;
      }
    }

    if (anyalpha) {
#pragma unroll
      for (int dt = 0; dt < 8; ++dt)
#pragma unroll
        for (int i = 0; i < 4; ++i) oacc[dt][i] *= alpha[i];
    }

    // ---- O += P V: B-operand from vfrag registers (compiler inserts the
    // counted vmcnt wait for vfrag here; no barrier, no LDS read for V).
    const f16x8 pa = *reinterpret_cast<const f16x8*>(&sP[wid][cl][g8]);
#pragma unroll
    for (int dt = 0; dt < 8; ++dt)
      oacc[dt] = __builtin_amdgcn_mfma_f32_16x16x32_f16(pa, vfrag[dt], oacc[dt], 0, 0, 0);

    // ---- drain this wave's K[kt+1] chunks; barrier joins all waves =>
    // K[kt+1] complete + visible, and all QK reads of sK[cur] are done
    // (safe for next iter's K[kt+2] -> sK[cur]).
    asm volatile("s_waitcnt vmcnt(0)" ::: "memory");
    __builtin_amdgcn_s_barrier();
    asm volatile("" ::: "memory");
  }

  // ---- epilogue
#pragma unroll
  for (int i = 0; i < 4; ++i) {
    const float inv_l = 1.0f / l_run[i];
    float* op = Og + ((size_t)b * SQ + (size_t)(q0 + wid * 16 + r0 + i)) * DH + cl;
#pragma unroll
    for (int dt = 0; dt < 8; ++dt)
      op[16 * dt] = oacc[dt][i] * inv_l;
  }
}

// ---------------- fallback (self-staging, QT=64, KT=64) ----------------
namespace {
constexpr int FKT  = 64;
constexpr int KSTR = DH + 8;
constexpr int VSTR = FKT + 8;
constexpr int FPSTR = FKT + 8;
}

__global__ __launch_bounds__(256, 2) void fused_attn_fb(
    const float* __restrict__ Qg, const float* __restrict__ Kg,
    const float* __restrict__ Vg, const float* __restrict__ Sg,
    float* __restrict__ Og)
{
  __shared__ alignas(16) _Float16 sKhi[FKT][KSTR];
  __shared__ alignas(16) _Float16 sKlo[FKT][KSTR];
  __shared__ alignas(16) _Float16 sVt[DH][VSTR];
  __shared__ alignas(16) _Float16 sP[4][16][FPSTR];

  const int tid  = threadIdx.x;
  const int wid  = tid >> 6;
  const int lane = tid & 63;
  const int cl   = lane & 15;
  const int g8   = (lane >> 4) * 8;
  const int r0   = (lane >> 4) * 4;

  const int b  = blockIdx.x >> 5;
  const int q0 = (blockIdx.x & 31) * 64;
  const float scale = Sg[b];

  f16x8 qhi[4], qlo[4];
  {
    const float* qp = Qg + ((size_t)b * SQ + q0 + wid * 16 + cl) * DH + g8;
#pragma unroll
    for (int ks = 0; ks < 4; ++ks) {
      const float4 a0 = *reinterpret_cast<const float4*>(qp + 32 * ks);
      const float4 a1 = *reinterpret_cast<const float4*>(qp + 32 * ks + 4);
      const float xs[8] = {a0.x, a0.y, a0.z, a0.w, a1.x, a1.y, a1.z, a1.w};
#pragma unroll
      for (int j = 0; j < 8; ++j) { qhi[ks][j] = hi16(xs[j]); qlo[ks][j] = lo16(xs[j]); }
    }
  }

  float m_run[4], l_run[4], alpha[4];
  f32x4 oacc[8];
#pragma unroll
  for (int i = 0; i < 4; ++i) { m_run[i] = -INFINITY; l_run[i] = 0.0f; }
#pragma unroll
  for (int dt = 0; dt < 8; ++dt) oacc[dt] = (f32x4){0.f, 0.f, 0.f, 0.f};

  for (int k0 = 0; k0 < SKV; k0 += FKT) {
    __syncthreads();
#pragma unroll
    for (int rep = 0; rep < 8; ++rep) {
      const int idx = tid + 256 * rep;
      const int row = idx >> 5;
      const int c4  = idx & 31;
      const float4 t = *reinterpret_cast<const float4*>(
          Kg + ((size_t)b * SKV + k0 + row) * DH + 4 * c4);
      f16x4 h4, l4;
      h4[0] = hi16(t.x); l4[0] = lo16(t.x);
      h4[1] = hi16(t.y); l4[1] = lo16(t.y);
      h4[2] = hi16(t.z); l4[2] = lo16(t.z);
      h4[3] = hi16(t.w); l4[3] = lo16(t.w);
      *reinterpret_cast<f16x4*>(&sKhi[row][4 * c4]) = h4;
      *reinterpret_cast<f16x4*>(&sKlo[row][4 * c4]) = l4;
    }
#pragma unroll
    for (int rep = 0; rep < 2; ++rep) {
      const int u  = tid + 256 * rep;
      const int du = u & 31;
      const int ku = u >> 5;
      const float* vb = Vg + ((size_t)b * SKV + k0 + 4 * ku) * DH + 4 * du;
      float4 t[4];
#pragma unroll
      for (int j = 0; j < 4; ++j)
        t[j] = *reinterpret_cast<const float4*>(vb + (size_t)j * DH);
#pragma unroll
      for (int dd = 0; dd < 4; ++dd) {
        const float v0 = (&t[0].x)[dd], v1 = (&t[1].x)[dd],
                    v2 = (&t[2].x)[dd], v3 = (&t[3].x)[dd];
        f16x4 w4 = {(_Float16)v0, (_Float16)v1, (_Float16)v2, (_Float16)v3};
        *reinterpret_cast<f16x4*>(&sVt[4 * du + dd][4 * ku]) = w4;
      }
    }
    __syncthreads();

    f32x4 sacc[4];
#pragma unroll
    for (int ct = 0; ct < 4; ++ct) {
      sacc[ct] = (f32x4){0.f, 0.f, 0.f, 0.f};
#pragma unroll
      for (int ks = 0; ks < 4; ++ks) {
        const f16x8 bhi = *reinterpret_cast<const f16x8*>(&sKhi[16 * ct + cl][32 * ks + g8]);
        const f16x8 blo = *reinterpret_cast<const f16x8*>(&sKlo[16 * ct + cl][32 * ks + g8]);
        sacc[ct] = __builtin_amdgcn_mfma_f32_16x16x32_f16(qhi[ks], bhi, sacc[ct], 0, 0, 0);
        sacc[ct] = __builtin_amdgcn_mfma_f32_16x16x32_f16(qlo[ks], bhi, sacc[ct], 0, 0, 0);
        sacc[ct] = __builtin_amdgcn_mfma_f32_16x16x32_f16(qhi[ks], blo, sacc[ct], 0, 0, 0);
      }
    }

    bool anyalpha = false;
#pragma unroll
    for (int i = 0; i < 4; ++i) {
      float mraw = fmaxf(fmaxf(sacc[0][i], sacc[1][i]), fmaxf(sacc[2][i], sacc[3][i]));
#pragma unroll
      for (int off = 8; off >= 1; off >>= 1)
        mraw = fmaxf(mraw, __shfl_xor(mraw, off, 64));
      const float mt = mraw * scale;
      if (mt >= m_run[i] - 9.21f) {
        const float mnew = fmaxf(m_run[i], mt);
        alpha[i] = __expf(m_run[i] - mnew);
        m_run[i] = mnew;
        const int qrow = q0 + wid * 16 + r0 + i;
        const uint32_t rowbase =
            ((uint32_t)b * (uint32_t)SQ + (uint32_t)qrow) * (uint32_t)SKV + (uint32_t)k0;
        float ps = 0.0f;
#pragma unroll
        for (int ct = 0; ct < 4; ++ct) {
          const float p = __expf(sacc[ct][i] * scale - mnew);
          ps += p;
          const bool keep = jax_keep(rowbase + (uint32_t)(16 * ct + cl));
          sP[wid][r0 + i][16 * ct + cl] = keep ? (_Float16)(p * (1.0f / 0.7f))
                                               : (_Float16)0.0f;
        }
#pragma unroll
        for (int off = 8; off >= 1; off >>= 1)
          ps += __shfl_xor(ps, off, 64);
        l_run[i] = l_run[i] * alpha[i] + ps;
        anyalpha |= (alpha[i] != 1.0f);
      } else {
        alpha[i] = 1.0f;
#pragma unroll
        for (int ct = 0; ct < 4; ++ct)
          sP[wid][r0 + i][16 * ct + cl] = (_Float16)0.0f;
      }
    }

    if (anyalpha) {
#pragma unroll
      for (int dt = 0; dt < 8; ++dt)
#pragma unroll
        for (int i = 0; i < 4; ++i) oacc[dt][i] *= alpha[i];
    }
#pragma unroll
    for (int ks2 = 0; ks2 < 2; ++ks2) {
      const f16x8 pa = *reinterpret_cast<const f16x8*>(&sP[wid][cl][32 * ks2 + g8]);
#pragma unroll
      for (int dt = 0; dt < 8; ++dt) {
        const f16x8 bv = *reinterpret_cast<const f16x8*>(&sVt[16 * dt + cl][32 * ks2 + g8]);
        oacc[dt] = __builtin_amdgcn_mfma_f32_16x16x32_f16(pa, bv, oacc[dt], 0, 0, 0);
      }
    }
  }

#pragma unroll
  for (int i = 0; i < 4; ++i) {
    const float inv_l = 1.0f / l_run[i];
    float* op = Og + ((size_t)b * SQ + (size_t)(q0 + wid * 16 + r0 + i)) * DH + cl;
#pragma unroll
    for (int dt = 0; dt < 8; ++dt)
      op[16 * dt] = oacc[dt][i] * inv_l;
  }
}

extern "C" void kernel_launch(void* const* d_in, const int* in_sizes, int n_in,
                              void* d_out, int out_size, void* d_ws, size_t ws_size,
                              hipStream_t stream) {
  (void)in_sizes; (void)n_in; (void)out_size;
  const float* q  = (const float*)d_in[0];
  const float* k  = (const float*)d_in[1];
  const float* v  = (const float*)d_in[2];
  const float* sc = (const float*)d_in[3];
  float* out = (float*)d_out;

  if (ws_size >= WS_NEED) {
    _Float16* ws = (_Float16*)d_ws;
    prep_tile<<<dim3(Bb * NKT), dim3(256), 0, stream>>>(k, v, ws);
    fused_attn5<<<dim3(Bb * (SQ / 64)), dim3(256), 0, stream>>>(q, ws, sc, out);
  } else {
    fused_attn_fb<<<dim3(Bb * (SQ / 64)), dim3(256), 0, stream>>>(q, k, v, sc, out);
  }
}

// Round 4
// 387.868 us; speedup vs baseline: 1.2402x; 1.2402x over previous
//
#include <hip/hip_runtime.h>
#include <stdint.h>

// R12: revert fused kernel to R8's proven structure (307us kernel) + three
// low-risk adds: (1) s_setprio(1) around QK and PV MFMA clusters (T5);
// (2) wave-uniform all-skip branch -- when all 16 rows of a wave take the
// fast path, P-tile is exactly zero: skip zero-writes + pa/bv reads + 8 PV
// MFMAs (exact-zero contribution, no numerics change); (3) prepass K-phase
// loads transposed directly from global (line-coalesced), dropping the K LDS
// round-trip + one barrier. R9/R10/R11 pipelining variants all lost TLP or
// added traffic and regressed; 4 blocks/CU + R8 flow is the verified optimum.

namespace {

constexpr int Bb  = 32;
constexpr int SQ  = 2048;
constexpr int SKV = 2048;
constexpr int DH  = 128;
constexpr int KT  = 32;
constexpr int NKT = SKV / KT;          // 64
constexpr int TILE_F16 = 12288;        // Khi 4096 | Klo 4096 | Vt 4096 (f16 elems)
constexpr size_t WS_NEED = (size_t)Bb * NKT * TILE_F16 * 2;  // 50,331,648 B
constexpr int PSTR = KT + 8;           // 40

typedef _Float16 f16x8 __attribute__((ext_vector_type(8)));
typedef _Float16 f16x4 __attribute__((ext_vector_type(4)));
typedef float    f32x4 __attribute__((ext_vector_type(4)));

__device__ __forceinline__ uint32_t rotl32(uint32_t x, int d) {
  return (x << d) | (x >> (32 - d));
}

// JAX threefry2x32, key=(0,42), counter=(0,i); partitionable bits = x0^x1.
__device__ __forceinline__ uint32_t jax_random_bits(uint32_t i) {
  constexpr uint32_t K0 = 0u;
  constexpr uint32_t K1 = 42u;
  constexpr uint32_t K2 = 0x1BD11BDAu ^ K0 ^ K1;
  uint32_t x0 = K0;
  uint32_t x1 = i + K1;
#define TF4(a,b,c,d) \
  x0 += x1; x1 = rotl32(x1,a); x1 ^= x0; \
  x0 += x1; x1 = rotl32(x1,b); x1 ^= x0; \
  x0 += x1; x1 = rotl32(x1,c); x1 ^= x0; \
  x0 += x1; x1 = rotl32(x1,d); x1 ^= x0;
  TF4(13,15,26,6)   x0 += K1; x1 += K2 + 1u;
  TF4(17,29,16,24)  x0 += K2; x1 += K0 + 2u;
  TF4(13,15,26,6)   x0 += K0; x1 += K1 + 3u;
  TF4(17,29,16,24)  x0 += K1; x1 += K2 + 4u;
  TF4(13,15,26,6)   x0 += K2; x1 += K0 + 5u;
#undef TF4
  return x0 ^ x1;
}

__device__ __forceinline__ bool jax_keep(uint32_t i) {
  const uint32_t fb = (jax_random_bits(i) >> 9) | 0x3f800000u;
  return (__uint_as_float(fb) - 1.0f) < 0.7f;
}

__device__ __forceinline__ _Float16 hi16(float x) { return (_Float16)x; }
__device__ __forceinline__ _Float16 lo16(float x) {
  return (_Float16)(x - (float)((_Float16)x));
}

} // namespace

// ------------- prepass: one block per (b,kt) 32-row tile -------------
__global__ __launch_bounds__(256) void prep_tile(const float* __restrict__ Kg,
                                                 const float* __restrict__ Vg,
                                                 _Float16* __restrict__ ws) {
  __shared__ alignas(16) float sT[KT][DH + 4];   // 16.9 KB, used by V phase

  const int tid  = threadIdx.x;
  const int b    = blockIdx.x >> 6;
  const int kt   = blockIdx.x & 63;
  _Float16* tile = ws + (size_t)(b * NKT + kt) * TILE_F16;

  // ---- phase K: DIRECT transposed global loads (no LDS round-trip).
  // Per 64-lane task f: 16 rows x 128B fully line-covered -> coalesced.
  {
    const float* kb = Kg + ((size_t)b * SKV + kt * KT) * DH;
#pragma unroll
    for (int rep = 0; rep < 2; ++rep) {
      const int task = tid + 256 * rep;     // 0..511
      const int lane = task & 63;
      const int f    = task >> 6;           // 0..7
      const int ks   = f >> 1;
      const int ct   = f & 1;
      const int cl   = lane & 15;
      const int g8   = (lane >> 4) * 8;
      const float* src = kb + (size_t)(ct * 16 + cl) * DH + ks * 32 + g8;
      const float4 a0 = *reinterpret_cast<const float4*>(src);
      const float4 a1 = *reinterpret_cast<const float4*>(src + 4);
      const float xs[8] = {a0.x, a0.y, a0.z, a0.w, a1.x, a1.y, a1.z, a1.w};
      f16x8 h, l;
#pragma unroll
      for (int j = 0; j < 8; ++j) { h[j] = hi16(xs[j]); l[j] = lo16(xs[j]); }
      *reinterpret_cast<f16x8*>(tile + f * 512 + lane * 8)        = h;
      *reinterpret_cast<f16x8*>(tile + 4096 + f * 512 + lane * 8) = l;
    }
  }

  // ---- phase V: coalesced load -> LDS, then fragment-linear transpose
  {
    const float* vb = Vg + ((size_t)b * SKV + kt * KT) * DH;
#pragma unroll
    for (int rep = 0; rep < 4; ++rep) {
      const int idx = tid + 256 * rep;
      const int row = idx >> 5;
      const int c4  = idx & 31;
      *reinterpret_cast<float4*>(&sT[row][4 * c4]) =
          *reinterpret_cast<const float4*>(vb + (size_t)row * DH + 4 * c4);
    }
  }
  __syncthreads();
  // V^T fragment-linear: frag = dt (0..7), elem j = V[g8+j][dt*16+cl]
#pragma unroll
  for (int rep = 0; rep < 2; ++rep) {
    const int task = tid + 256 * rep;
    const int lane = task & 63;
    const int dt   = task >> 6;           // 0..7
    const int cl   = lane & 15;
    const int g8   = (lane >> 4) * 8;
    f16x8 w;
#pragma unroll
    for (int j = 0; j < 8; ++j)
      w[j] = (_Float16)sT[g8 + j][dt * 16 + cl];
    *reinterpret_cast<f16x8*>(tile + 8192 + dt * 512 + lane * 8) = w;
  }
}

// ---------------- main fused kernel: QT=64, KT=32 (R8 structure) ----------------
__global__ __launch_bounds__(256, 3) void fused_attn5(
    const float* __restrict__ Qg, const _Float16* __restrict__ Wk,
    const float* __restrict__ Sg, float* __restrict__ Og)
{
  __shared__ alignas(16) _Float16 sStage[TILE_F16];   // 24 KB: Khi|Klo|Vt
  __shared__ alignas(16) _Float16 sP[4][16][PSTR];    // 5.1 KB (wave-private)

  const int tid  = threadIdx.x;
  const int wid  = tid >> 6;
  const int lane = tid & 63;
  const int cl   = lane & 15;
  const int g8   = (lane >> 4) * 8;
  const int r0   = (lane >> 4) * 4;

  const int b  = blockIdx.x >> 5;
  const int q0 = (blockIdx.x & 31) * 64;
  const float scale = Sg[b];

  // Q A-fragments (hi/lo) in registers: rows q0+wid*16+cl
  f16x8 qhi[4], qlo[4];
  {
    const float* qp = Qg + ((size_t)b * SQ + q0 + wid * 16 + cl) * DH + g8;
#pragma unroll
    for (int ks = 0; ks < 4; ++ks) {
      const float4 a0 = *reinterpret_cast<const float4*>(qp + 32 * ks);
      const float4 a1 = *reinterpret_cast<const float4*>(qp + 32 * ks + 4);
      const float xs[8] = {a0.x, a0.y, a0.z, a0.w, a1.x, a1.y, a1.z, a1.w};
#pragma unroll
      for (int j = 0; j < 8; ++j) { qhi[ks][j] = hi16(xs[j]); qlo[ks][j] = lo16(xs[j]); }
    }
  }

  float m_run[4], l_run[4], alpha[4];
  f32x4 oacc[8];
#pragma unroll
  for (int i = 0; i < 4; ++i) { m_run[i] = -INFINITY; l_run[i] = 0.0f; }
#pragma unroll
  for (int dt = 0; dt < 8; ++dt) oacc[dt] = (f32x4){0.f, 0.f, 0.f, 0.f};

  for (int kt = 0; kt < NKT; ++kt) {
    __syncthreads();   // prev iter's reads of sStage done

    // ---- DMA stage 24 KB: 24 chunks of 1 KB, 6 per wave
    const uint32_t* tsrc =
        reinterpret_cast<const uint32_t*>(Wk + (size_t)(b * NKT + kt) * TILE_F16);
#pragma unroll
    for (int c = 0; c < 6; ++c) {
      const int j = wid + 4 * c;
      __builtin_amdgcn_global_load_lds(tsrc + j * 256 + lane * 4,
          reinterpret_cast<uint32_t*>(&sStage[j * 512]), 16, 0, 0);
    }
    __syncthreads();   // tile visible

    // ---- S = Q K^T (fp16 hi/lo, fp32 accum): 16x32 per wave
    f32x4 sacc[2];
    __builtin_amdgcn_s_setprio(1);
#pragma unroll
    for (int ct = 0; ct < 2; ++ct) {
      sacc[ct] = (f32x4){0.f, 0.f, 0.f, 0.f};
#pragma unroll
      for (int ks = 0; ks < 4; ++ks) {
        const int f = ks * 2 + ct;
        const f16x8 bhi = *reinterpret_cast<const f16x8*>(&sStage[f * 512 + lane * 8]);
        const f16x8 blo = *reinterpret_cast<const f16x8*>(&sStage[4096 + f * 512 + lane * 8]);
        sacc[ct] = __builtin_amdgcn_mfma_f32_16x16x32_f16(qhi[ks], bhi, sacc[ct], 0, 0, 0);
        sacc[ct] = __builtin_amdgcn_mfma_f32_16x16x32_f16(qlo[ks], bhi, sacc[ct], 0, 0, 0);
        sacc[ct] = __builtin_amdgcn_mfma_f32_16x16x32_f16(qhi[ks], blo, sacc[ct], 0, 0, 0);
      }
    }
    __builtin_amdgcn_s_setprio(0);

    // ---- online softmax, per-row fast-path (R6 control flow); zero-writes
    // for skipped rows deferred until we know the wave isn't all-skip.
    bool anyalpha = false;
    bool tk[4];
#pragma unroll
    for (int i = 0; i < 4; ++i) {
      float mraw = fmaxf(sacc[0][i], sacc[1][i]);
#pragma unroll
      for (int off = 8; off >= 1; off >>= 1)
        mraw = fmaxf(mraw, __shfl_xor(mraw, off, 64));
      const float mt = mraw * scale;

      tk[i] = (mt >= m_run[i] - 9.21f);   // 16-lane-group-uniform per row
      if (tk[i]) {
        const float mnew = fmaxf(m_run[i], mt);
        alpha[i] = __expf(m_run[i] - mnew);
        m_run[i] = mnew;
        const int qrow = q0 + wid * 16 + r0 + i;
        const uint32_t rowbase =
            ((uint32_t)b * (uint32_t)SQ + (uint32_t)qrow) * (uint32_t)SKV
            + (uint32_t)(kt * KT);
        float ps = 0.0f;
#pragma unroll
        for (int ct = 0; ct < 2; ++ct) {
          const float p = __expf(sacc[ct][i] * scale - mnew);
          ps += p;
          const bool keep = jax_keep(rowbase + (uint32_t)(16 * ct + cl));
          sP[wid][r0 + i][16 * ct + cl] = keep ? (_Float16)(p * (1.0f / 0.7f))
                                               : (_Float16)0.0f;
        }
#pragma unroll
        for (int off = 8; off >= 1; off >>= 1)
          ps += __shfl_xor(ps, off, 64);
        l_run[i] = l_run[i] * alpha[i] + ps;
        anyalpha |= (alpha[i] != 1.0f);
      } else {
        alpha[i] = 1.0f;
      }
    }

    // ---- wave-uniform all-skip: P-tile exactly zero -> PV adds nothing.
    const int myAllSkip = !(tk[0] || tk[1] || tk[2] || tk[3]);
    if (!__all(myAllSkip)) {
      // write zeros for the skipped rows (PV reads every row of sP)
#pragma unroll
      for (int i = 0; i < 4; ++i) {
        if (!tk[i]) {
#pragma unroll
          for (int ct = 0; ct < 2; ++ct)
            sP[wid][r0 + i][16 * ct + cl] = (_Float16)0.0f;
        }
      }

      if (anyalpha) {
#pragma unroll
        for (int dt = 0; dt < 8; ++dt)
#pragma unroll
          for (int i = 0; i < 4; ++i) oacc[dt][i] *= alpha[i];
      }

      // ---- O += P V (k=32, one MFMA per dt); sP wave-private
      const f16x8 pa = *reinterpret_cast<const f16x8*>(&sP[wid][cl][g8]);
      __builtin_amdgcn_s_setprio(1);
#pragma unroll
      for (int dt = 0; dt < 8; ++dt) {
        const f16x8 bv = *reinterpret_cast<const f16x8*>(
            &sStage[8192 + dt * 512 + lane * 8]);
        oacc[dt] = __builtin_amdgcn_mfma_f32_16x16x32_f16(pa, bv, oacc[dt], 0, 0, 0);
      }
      __builtin_amdgcn_s_setprio(0);
    }
  }

  // ---- epilogue
#pragma unroll
  for (int i = 0; i < 4; ++i) {
    const float inv_l = 1.0f / l_run[i];
    float* op = Og + ((size_t)b * SQ + (size_t)(q0 + wid * 16 + r0 + i)) * DH + cl;
#pragma unroll
    for (int dt = 0; dt < 8; ++dt)
      op[16 * dt] = oacc[dt][i] * inv_l;
  }
}

// ---------------- fallback (self-staging, QT=64, KT=64) ----------------
namespace {
constexpr int FKT  = 64;
constexpr int KSTR = DH + 8;
constexpr int VSTR = FKT + 8;
constexpr int FPSTR = FKT + 8;
}

__global__ __launch_bounds__(256, 2) void fused_attn_fb(
    const float* __restrict__ Qg, const float* __restrict__ Kg,
    const float* __restrict__ Vg, const float* __restrict__ Sg,
    float* __restrict__ Og)
{
  __shared__ alignas(16) _Float16 sKhi[FKT][KSTR];
  __shared__ alignas(16) _Float16 sKlo[FKT][KSTR];
  __shared__ alignas(16) _Float16 sVt[DH][VSTR];
  __shared__ alignas(16) _Float16 sP[4][16][FPSTR];

  const int tid  = threadIdx.x;
  const int wid  = tid >> 6;
  const int lane = tid & 63;
  const int cl   = lane & 15;
  const int g8   = (lane >> 4) * 8;
  const int r0   = (lane >> 4) * 4;

  const int b  = blockIdx.x >> 5;
  const int q0 = (blockIdx.x & 31) * 64;
  const float scale = Sg[b];

  f16x8 qhi[4], qlo[4];
  {
    const float* qp = Qg + ((size_t)b * SQ + q0 + wid * 16 + cl) * DH + g8;
#pragma unroll
    for (int ks = 0; ks < 4; ++ks) {
      const float4 a0 = *reinterpret_cast<const float4*>(qp + 32 * ks);
      const float4 a1 = *reinterpret_cast<const float4*>(qp + 32 * ks + 4);
      const float xs[8] = {a0.x, a0.y, a0.z, a0.w, a1.x, a1.y, a1.z, a1.w};
#pragma unroll
      for (int j = 0; j < 8; ++j) { qhi[ks][j] = hi16(xs[j]); qlo[ks][j] = lo16(xs[j]); }
    }
  }

  float m_run[4], l_run[4], alpha[4];
  f32x4 oacc[8];
#pragma unroll
  for (int i = 0; i < 4; ++i) { m_run[i] = -INFINITY; l_run[i] = 0.0f; }
#pragma unroll
  for (int dt = 0; dt < 8; ++dt) oacc[dt] = (f32x4){0.f, 0.f, 0.f, 0.f};

  for (int k0 = 0; k0 < SKV; k0 += FKT) {
    __syncthreads();
#pragma unroll
    for (int rep = 0; rep < 8; ++rep) {
      const int idx = tid + 256 * rep;
      const int row = idx >> 5;
      const int c4  = idx & 31;
      const float4 t = *reinterpret_cast<const float4*>(
          Kg + ((size_t)b * SKV + k0 + row) * DH + 4 * c4);
      f16x4 h4, l4;
      h4[0] = hi16(t.x); l4[0] = lo16(t.x);
      h4[1] = hi16(t.y); l4[1] = lo16(t.y);
      h4[2] = hi16(t.z); l4[2] = lo16(t.z);
      h4[3] = hi16(t.w); l4[3] = lo16(t.w);
      *reinterpret_cast<f16x4*>(&sKhi[row][4 * c4]) = h4;
      *reinterpret_cast<f16x4*>(&sKlo[row][4 * c4]) = l4;
    }
#pragma unroll
    for (int rep = 0; rep < 2; ++rep) {
      const int u  = tid + 256 * rep;
      const int du = u & 31;
      const int ku = u >> 5;
      const float* vb = Vg + ((size_t)b * SKV + k0 + 4 * ku) * DH + 4 * du;
      float4 t[4];
#pragma unroll
      for (int j = 0; j < 4; ++j)
        t[j] = *reinterpret_cast<const float4*>(vb + (size_t)j * DH);
#pragma unroll
      for (int dd = 0; dd < 4; ++dd) {
        const float v0 = (&t[0].x)[dd], v1 = (&t[1].x)[dd],
                    v2 = (&t[2].x)[dd], v3 = (&t[3].x)[dd];
        f16x4 w4 = {(_Float16)v0, (_Float16)v1, (_Float16)v2, (_Float16)v3};
        *reinterpret_cast<f16x4*>(&sVt[4 * du + dd][4 * ku]) = w4;
      }
    }
    __syncthreads();

    f32x4 sacc[4];
#pragma unroll
    for (int ct = 0; ct < 4; ++ct) {
      sacc[ct] = (f32x4){0.f, 0.f, 0.f, 0.f};
#pragma unroll
      for (int ks = 0; ks < 4; ++ks) {
        const f16x8 bhi = *reinterpret_cast<const f16x8*>(&sKhi[16 * ct + cl][32 * ks + g8]);
        const f16x8 blo = *reinterpret_cast<const f16x8*>(&sKlo[16 * ct + cl][32 * ks + g8]);
        sacc[ct] = __builtin_amdgcn_mfma_f32_16x16x32_f16(qhi[ks], bhi, sacc[ct], 0, 0, 0);
        sacc[ct] = __builtin_amdgcn_mfma_f32_16x16x32_f16(qlo[ks], bhi, sacc[ct], 0, 0, 0);
        sacc[ct] = __builtin_amdgcn_mfma_f32_16x16x32_f16(qhi[ks], blo, sacc[ct], 0, 0, 0);
      }
    }

    bool anyalpha = false;
#pragma unroll
    for (int i = 0; i < 4; ++i) {
      float mraw = fmaxf(fmaxf(sacc[0][i], sacc[1][i]), fmaxf(sacc[2][i], sacc[3][i]));
#pragma unroll
      for (int off = 8; off >= 1; off >>= 1)
        mraw = fmaxf(mraw, __shfl_xor(mraw, off, 64));
      const float mt = mraw * scale;
      if (mt >= m_run[i] - 9.21f) {
        const float mnew = fmaxf(m_run[i], mt);
        alpha[i] = __expf(m_run[i] - mnew);
        m_run[i] = mnew;
        const int qrow = q0 + wid * 16 + r0 + i;
        const uint32_t rowbase =
            ((uint32_t)b * (uint32_t)SQ + (uint32_t)qrow) * (uint32_t)SKV + (uint32_t)k0;
        float ps = 0.0f;
#pragma unroll
        for (int ct = 0; ct < 4; ++ct) {
          const float p = __expf(sacc[ct][i] * scale - mnew);
          ps += p;
          const bool keep = jax_keep(rowbase + (uint32_t)(16 * ct + cl));
          sP[wid][r0 + i][16 * ct + cl] = keep ? (_Float16)(p * (1.0f / 0.7f))
                                               : (_Float16)0.0f;
        }
#pragma unroll
        for (int off = 8; off >= 1; off >>= 1)
          ps += __shfl_xor(ps, off, 64);
        l_run[i] = l_run[i] * alpha[i] + ps;
        anyalpha |= (alpha[i] != 1.0f);
      } else {
        alpha[i] = 1.0f;
#pragma unroll
        for (int ct = 0; ct < 4; ++ct)
          sP[wid][r0 + i][16 * ct + cl] = (_Float16)0.0f;
      }
    }

    if (anyalpha) {
#pragma unroll
      for (int dt = 0; dt < 8; ++dt)
#pragma unroll
        for (int i = 0; i < 4; ++i) oacc[dt][i] *= alpha[i];
    }
#pragma unroll
    for (int ks2 = 0; ks2 < 2; ++ks2) {
      const f16x8 pa = *reinterpret_cast<const f16x8*>(&sP[wid][cl][32 * ks2 + g8]);
#pragma unroll
      for (int dt = 0; dt < 8; ++dt) {
        const f16x8 bv = *reinterpret_cast<const f16x8*>(&sVt[16 * dt + cl][32 * ks2 + g8]);
        oacc[dt] = __builtin_amdgcn_mfma_f32_16x16x32_f16(pa, bv, oacc[dt], 0, 0, 0);
      }
    }
  }

#pragma unroll
  for (int i = 0; i < 4; ++i) {
    const float inv_l = 1.0f / l_run[i];
    float* op = Og + ((size_t)b * SQ + (size_t)(q0 + wid * 16 + r0 + i)) * DH + cl;
#pragma unroll
    for (int dt = 0; dt < 8; ++dt)
      op[16 * dt] = oacc[dt][i] * inv_l;
  }
}

extern "C" void kernel_launch(void* const* d_in, const int* in_sizes, int n_in,
                              void* d_out, int out_size, void* d_ws, size_t ws_size,
                              hipStream_t stream) {
  (void)in_sizes; (void)n_in; (void)out_size;
  const float* q  = (const float*)d_in[0];
  const float* k  = (const float*)d_in[1];
  const float* v  = (const float*)d_in[2];
  const float* sc = (const float*)d_in[3];
  float* out = (float*)d_out;

  if (ws_size >= WS_NEED) {
    _Float16* ws = (_Float16*)d_ws;
    prep_tile<<<dim3(Bb * NKT), dim3(256), 0, stream>>>(k, v, ws);
    fused_attn5<<<dim3(Bb * (SQ / 64)), dim3(256), 0, stream>>>(q, ws, sc, out);
  } else {
    fused_attn_fb<<<dim3(Bb * (SQ / 64)), dim3(256), 0, stream>>>(q, k, v, sc, out);
  }
}